// Round 2
// baseline (91.473 us; speedup 1.0000x reference)
//
#include <hip/hip_runtime.h>
#include <cfloat>

// Problem constants: B=32, C=256, L=512, N=1024, S=8
constexpr int Cc = 256;
constexpr int Lc = 512;
constexpr int Nc = 1024;
constexpr int Sc = 8;

constexpr int CT = 32;              // channels staged per block
constexpr int LDS_STRIDE = Lc + 1;  // +1 float pad: bank = (c + q) % 32, ~2-way max aliasing (free)

// Block = one ROI x 32-channel tile, 256 threads.
// Phase 1: coalesced global->LDS staging of the ROI's row segments.
// Phase 2: per-thread (channel, bin) max over LDS (4B-banked, no cache-line penalty).
__global__ __launch_bounds__(256) void roi_pool_lds(
    const float* __restrict__ sentences,   // (B, C, L)
    const int*   __restrict__ rois,        // (N, 2)
    const int*   __restrict__ roi_idx,     // (N,)
    float*       __restrict__ out)         // (N, C, S)
{
    __shared__ float lds[CT * LDS_STRIDE]; // 65.7 KB -> 2 blocks/CU

    const int blk  = blockIdx.x;           // 0 .. N*8-1
    const int n    = blk >> 3;
    const int tile = blk & 7;
    const int c0   = tile * CT;

    const int x1 = rois[2 * n];            // wave-uniform scalar loads
    const int x2 = rois[2 * n + 1];
    const int lr = x2 - x1;                // 1 .. 512
    const int b  = roi_idx[n];

    const int tid  = threadIdx.x;
    const int lane = tid & 63;
    const int wid  = tid >> 6;             // 0..3

    // ---- Phase 1: stage rows c0..c0+31, columns [x1, x2) ----
    const float* src = sentences + ((size_t)b * Cc + c0) * Lc + x1;
    for (int r = wid; r < CT; r += 4) {
        const float* rowp = src + r * Lc;
        float* drow = lds + r * LDS_STRIDE;
        for (int q = lane; q < lr; q += 64)   // 64 lanes contiguous: ~4-5 lines/inst
            drow[q] = rowp[q];
    }
    __syncthreads();

    // ---- Phase 2: per-thread bin max ----
    const int cl = tid >> 3;               // 0..31 channel within tile
    const int j  = tid & 7;                // bin
    const int s  = (j * lr) >> 3;                  // j*lr // S        (relative)
    const int e  = ((j + 1) * lr + Sc - 1) >> 3;   // ceil((j+1)lr/S)  (<= lr)

    const float* lrow = lds + cl * LDS_STRIDE;
    float m = -FLT_MAX;
    for (int q = s; q < e; ++q)
        m = fmaxf(m, lrow[q]);

    // out flat index = n*2048 + (c0+cl)*8 + j = n*2048 + tile*256 + tid  (coalesced)
    out[(size_t)n * (Cc * Sc) + tile * 256 + tid] = m;
}

extern "C" void kernel_launch(void* const* d_in, const int* in_sizes, int n_in,
                              void* d_out, int out_size, void* d_ws, size_t ws_size,
                              hipStream_t stream) {
    const float* sentences = (const float*)d_in[0];
    const int*   rois      = (const int*)d_in[1];
    const int*   roi_idx   = (const int*)d_in[2];
    float*       out       = (float*)d_out;

    const int grid = Nc * 8;   // 8192 blocks, one ROI x channel-tile each
    roi_pool_lds<<<grid, 256, 0, stream>>>(sentences, rois, roi_idx, out);
}

// Round 3
// 76.854 us; speedup vs baseline: 1.1902x; 1.1902x over previous
//
#include <hip/hip_runtime.h>
#include <cfloat>

// Problem constants: B=32, C=256, L=512, N=1024, S=8
constexpr int Cc = 256;
constexpr int Lc = 512;
constexpr int Nc = 1024;
constexpr int Sc = 8;

typedef float f4 __attribute__((ext_vector_type(4)));

// Max over elements k in [lo, hi) of chunk v, merged with m.
// lo/hi are WAVE-UNIFORM (derived from block-uniform x1/x2) -> scalar cmps,
// v_cndmask selects, no divergence.
__device__ __forceinline__ float chunkmax(f4 v, int lo, int hi, float m) {
    float a0 = (lo <= 0 && 0 < hi) ? v.x : -FLT_MAX;
    float a1 = (lo <= 1 && 1 < hi) ? v.y : -FLT_MAX;
    float a2 = (lo <= 2 && 2 < hi) ? v.z : -FLT_MAX;
    float a3 = (lo <= 3 && 3 < hi) ? v.w : -FLT_MAX;
    return fmaxf(fmaxf(m, fmaxf(a0, a1)), fmaxf(a2, a3));
}

// Block = one ROI, thread = one channel. Single pass over the row segment
// [x1 & ~3, x2) in 16B-aligned float4 chunks; each chunk loaded exactly once
// (boundary chunk stays in a register across adjacent bins). Bins statically
// unrolled -> accumulators stay in VGPRs (no runtime indexing).
__global__ __launch_bounds__(256) void roi_pool_rowwalk(
    const float* __restrict__ sentences,   // (B, C, L)
    const int*   __restrict__ rois,        // (N, 2)
    const int*   __restrict__ roi_idx,     // (N,)
    float*       __restrict__ out)         // (N, C, S)
{
    const int n = blockIdx.x;
    const int c = threadIdx.x;

    const int x1 = rois[2 * n];            // block-uniform scalar loads
    const int x2 = rois[2 * n + 1];
    const int lr = x2 - x1;                // 1 .. 512
    const int b  = roi_idx[n];

    const float* R = sentences + ((size_t)b * Cc + c) * Lc;

    int p = x1 & ~3;                       // 16B-aligned chunk cursor
    f4 v = *(const f4*)(R + p);

    float res[Sc];                         // static indices only (full unroll)
    #pragma unroll
    for (int j = 0; j < Sc; ++j) {
        const int s = x1 + ((j * lr) >> 3);                 // bin start
        const int e = x1 + (((j + 1) * lr + Sc - 1) >> 3);  // bin end (ceil)
        // head: elements of the current (possibly shared) chunk in [s, e)
        float m = chunkmax(v, s - p, min(e - p, 4), -FLT_MAX);
        // remaining chunks of this bin; invariant on exit: p < e <= p+4,
        // so the last chunk is retained for the next bin's head.
        while (p + 4 < e) {
            p += 4;
            v = *(const f4*)(R + p);
            m = chunkmax(v, 0, min(e - p, 4), m);
        }
        res[j] = m;
    }

    // out[(n*C + c)*S + j]: 8 consecutive floats -> two aligned f4 stores
    f4* o = (f4*)(out + ((size_t)n * Cc + c) * Sc);
    f4 r0 = {res[0], res[1], res[2], res[3]};
    f4 r1 = {res[4], res[5], res[6], res[7]};
    o[0] = r0;
    o[1] = r1;
}

extern "C" void kernel_launch(void* const* d_in, const int* in_sizes, int n_in,
                              void* d_out, int out_size, void* d_ws, size_t ws_size,
                              hipStream_t stream) {
    const float* sentences = (const float*)d_in[0];
    const int*   rois      = (const int*)d_in[1];
    const int*   roi_idx   = (const int*)d_in[2];
    float*       out       = (float*)d_out;

    roi_pool_rowwalk<<<Nc, Cc, 0, stream>>>(sentences, rois, roi_idx, out);
}

// Round 4
// 33.857 us; speedup vs baseline: 2.7017x; 2.2699x over previous
//
#include <hip/hip_runtime.h>
#include <cfloat>

// Problem constants: B=32, C=256, L=512, N=1024, S=8
constexpr int Cc = 256;
constexpr int Lc = 512;
constexpr int Nc = 1024;
constexpr int Sc = 8;

typedef float f4 __attribute__((ext_vector_type(4)));

__device__ __forceinline__ float max4(f4 v, float m) {
    return fmaxf(fmaxf(fmaxf(v.x, v.y), fmaxf(v.z, v.w)), m);
}

// Max over elements k in [lo, hi) of chunk v, merged with m (partial chunks).
__device__ __forceinline__ float chunkmax(f4 v, int lo, int hi, float m) {
    float a0 = (lo <= 0 && 0 < hi) ? v.x : -FLT_MAX;
    float a1 = (lo <= 1 && 1 < hi) ? v.y : -FLT_MAX;
    float a2 = (lo <= 2 && 2 < hi) ? v.z : -FLT_MAX;
    float a3 = (lo <= 3 && 3 < hi) ? v.w : -FLT_MAX;
    return fmaxf(fmaxf(m, fmaxf(a0, a1)), fmaxf(a2, a3));
}

// Thread per output element (n, c, j) — R1's high-occupancy layout —
// but each bin segment is walked in 16B-aligned float4 chunks with a
// 4-wide unrolled interior (4 independent loads in flight).
__global__ __launch_bounds__(256) void roi_pool_binvec(
    const float* __restrict__ sentences,   // (B, C, L)
    const int*   __restrict__ rois,        // (N, 2)
    const int*   __restrict__ roi_idx,     // (N,)
    float*       __restrict__ out)         // (N, C, S)
{
    const int blk  = blockIdx.x;                      // 0 .. N*8-1
    const int n    = blk >> 3;                        // 8 blocks per ROI
    const int base = ((blk & 7) << 8) | threadIdx.x;  // 0 .. 2047 within ROI
    const int c    = base >> 3;
    const int j    = base & 7;

    const int x1 = rois[2 * n];           // block-uniform scalar loads
    const int x2 = rois[2 * n + 1];
    const int lr = x2 - x1;               // 1 .. 512
    const int b  = roi_idx[n];

    const int s = x1 + ((j * lr) >> 3);                 // bin start
    const int e = x1 + (((j + 1) * lr + Sc - 1) >> 3);  // bin end (> s always)

    const float* R = sentences + ((size_t)b * Cc + c) * Lc;

    // head chunk (masked at start, and at end if the bin is single-chunk)
    int p = s & ~3;                        // aligned; chunk never crosses row end
    f4 v0 = *(const f4*)(R + p);
    float m = chunkmax(v0, s - p, min(e - p, 4), -FLT_MAX);
    p += 4;

    // interior: 4 full chunks per iteration, independent loads + partial maxes
    float m0 = -FLT_MAX, m1 = -FLT_MAX, m2 = -FLT_MAX, m3 = -FLT_MAX;
    while (p + 16 <= e) {
        f4 a = *(const f4*)(R + p);
        f4 bq = *(const f4*)(R + p + 4);
        f4 cq = *(const f4*)(R + p + 8);
        f4 dq = *(const f4*)(R + p + 12);
        m0 = max4(a, m0);
        m1 = max4(bq, m1);
        m2 = max4(cq, m2);
        m3 = max4(dq, m3);
        p += 16;
    }
    m = fmaxf(m, fmaxf(fmaxf(m0, m1), fmaxf(m2, m3)));

    // tail: up to 3 full chunks + one end-masked chunk
    while (p < e) {
        f4 t = *(const f4*)(R + p);
        m = chunkmax(t, 0, min(e - p, 4), m);
        p += 4;
    }

    // flat out index = n*2048 + c*8 + j = n*2048 + base  (coalesced)
    out[(size_t)n * (Cc * Sc) + base] = m;
}

extern "C" void kernel_launch(void* const* d_in, const int* in_sizes, int n_in,
                              void* d_out, int out_size, void* d_ws, size_t ws_size,
                              hipStream_t stream) {
    const float* sentences = (const float*)d_in[0];
    const int*   rois      = (const int*)d_in[1];
    const int*   roi_idx   = (const int*)d_in[2];
    float*       out       = (float*)d_out;

    const int grid = Nc * 8;   // 8192 blocks x 256 threads = one thread per output
    roi_pool_binvec<<<grid, 256, 0, stream>>>(sentences, rois, roi_idx, out);
}